// Round 5
// baseline (289.129 us; speedup 1.0000x reference)
//
#include <hip/hip_runtime.h>

// GroupLasso collapses to: out = 0.12f * (sum(w*w) + sum(b*b))
//   ROOT_GAMMA + COARSE_GAMMA + FINE_GAMMA = 0.02 + 0.04 + 0.06 = 0.12
// (segment_sum summed over all segments == total sum; coarse_map is irrelevant)
//
// R3 post-mortem: agent-scope release/acquire atomics -> per-block L2
// writeback/invalidate storm, 262 us @ 4.9% HBM. R4 (plain atomicAdd): fixed,
// kernel off top-5 (<118 us), total 287 us (harness fill/restore dominated).
// R5: int32 indexing (halve 64-bit addr VALU) + 2-way unrolled independent
// load streams. Same atomic scheme as R4 (known good).

constexpr int BLOCK = 256;
constexpr int GRID  = 2048;

__global__ __launch_bounds__(BLOCK) void grouplasso_sumsq(
    const float4* __restrict__ w4, int nw4,
    const float4* __restrict__ b4, int nb4,
    float* __restrict__ out)
{
    const int stride = GRID * BLOCK;                    // 524288
    const int tid    = blockIdx.x * BLOCK + threadIdx.x;

    float a0 = 0.f, a1 = 0.f;

    // weights: 2-way unrolled grid-stride, independent load streams
    int i = tid;
    for (; i + stride < nw4; i += 2 * stride) {
        float4 v0 = w4[i];
        float4 v1 = w4[i + stride];
        a0 = fmaf(v0.x, v0.x, a0); a0 = fmaf(v0.y, v0.y, a0);
        a0 = fmaf(v0.z, v0.z, a0); a0 = fmaf(v0.w, v0.w, a0);
        a1 = fmaf(v1.x, v1.x, a1); a1 = fmaf(v1.y, v1.y, a1);
        a1 = fmaf(v1.z, v1.z, a1); a1 = fmaf(v1.w, v1.w, a1);
    }
    for (; i < nw4; i += stride) {
        float4 v = w4[i];
        a0 = fmaf(v.x, v.x, a0); a0 = fmaf(v.y, v.y, a0);
        a0 = fmaf(v.z, v.z, a0); a0 = fmaf(v.w, v.w, a0);
    }
    // bias (small: 25000 float4)
    for (int j = tid; j < nb4; j += stride) {
        float4 v = b4[j];
        a1 = fmaf(v.x, v.x, a1); a1 = fmaf(v.y, v.y, a1);
        a1 = fmaf(v.z, v.z, a1); a1 = fmaf(v.w, v.w, a1);
    }

    float acc = a0 + a1;

    // block reduce: wave64 shuffle + LDS across 4 waves
    #pragma unroll
    for (int off = 32; off > 0; off >>= 1)
        acc += __shfl_down(acc, off, 64);
    __shared__ float smem[BLOCK / 64];
    const int lane = threadIdx.x & 63;
    const int wave = threadIdx.x >> 6;
    if (lane == 0) smem[wave] = acc;
    __syncthreads();

    if (threadIdx.x == 0) {
        float s = smem[0] + smem[1] + smem[2] + smem[3];
        atomicAdd(out, 0.12f * s);   // device-scope HW fp32 atomic, no fences
    }
}

extern "C" void kernel_launch(void* const* d_in, const int* in_sizes, int n_in,
                              void* d_out, int out_size, void* d_ws, size_t ws_size,
                              hipStream_t stream) {
    const float* w = (const float*)d_in[0];   // fc_weights, NUM_FINE*FEAT_DIM fp32
    const float* b = (const float*)d_in[1];   // fc_bias, NUM_FINE fp32
    // d_in[2] (coarse_map) is mathematically irrelevant — see header comment.

    const int nw4 = in_sizes[0] >> 2;   // 12.8e6, fits int
    const int nb4 = in_sizes[1] >> 2;   // 25000

    float* out = (float*)d_out;

    // d_out is re-poisoned to 0xAA before every timed launch — zero it with a
    // graph-legal async memset node, then accumulate into it atomically.
    hipMemsetAsync(out, 0, sizeof(float), stream);
    grouplasso_sumsq<<<GRID, BLOCK, 0, stream>>>(
        (const float4*)w, nw4, (const float4*)b, nb4, out);
}

// Round 6
// 275.843 us; speedup vs baseline: 1.0482x; 1.0482x over previous
//
#include <hip/hip_runtime.h>

// GroupLasso collapses to: out = 0.12f * (sum(w*w) + sum(b*b))
//   ROOT_GAMMA + COARSE_GAMMA + FINE_GAMMA = 0.02 + 0.04 + 0.06 = 0.12
// (segment_sum summed over all segments == total sum; coarse_map is irrelevant)
//
// History: R3 agent-scope atomics -> L2 coherence storm (262us @ 4.9% HBM).
// R4/R5 plain single-address atomicAdd + memset node: 287-289us. R1 two-kernel
// deterministic: 273.7us. Theory: 2048 same-address atomics serialize at the
// coherence point (~13us tail) + memset node latency. R6: revert to the R1
// two-kernel structure (no atomics, no memset) with int32 indexing kept.

constexpr int BLOCK = 256;
constexpr int GRID1 = 2048;

__device__ __forceinline__ float block_reduce(float acc) {
    #pragma unroll
    for (int off = 32; off > 0; off >>= 1)
        acc += __shfl_down(acc, off, 64);
    __shared__ float smem[BLOCK / 64];
    const int lane = threadIdx.x & 63;
    const int wave = threadIdx.x >> 6;
    if (lane == 0) smem[wave] = acc;
    __syncthreads();
    float s = 0.f;
    if (threadIdx.x == 0) {
        #pragma unroll
        for (int w = 0; w < BLOCK / 64; ++w) s += smem[w];
    }
    return s;  // valid only on thread 0
}

__global__ __launch_bounds__(BLOCK) void sq_partial_kernel(
    const float4* __restrict__ w4, int nw4,
    const float4* __restrict__ b4, int nb4,
    float* __restrict__ partials)
{
    const int stride = GRID1 * BLOCK;                   // 524288
    const int tid    = blockIdx.x * BLOCK + threadIdx.x;

    float acc = 0.f;

    // weights: simple grid-stride float4 (coalesced 16 B/lane)
    for (int i = tid; i < nw4; i += stride) {
        float4 v = w4[i];
        acc = fmaf(v.x, v.x, acc);
        acc = fmaf(v.y, v.y, acc);
        acc = fmaf(v.z, v.z, acc);
        acc = fmaf(v.w, v.w, acc);
    }
    // bias (small: 25000 float4)
    for (int j = tid; j < nb4; j += stride) {
        float4 v = b4[j];
        acc = fmaf(v.x, v.x, acc);
        acc = fmaf(v.y, v.y, acc);
        acc = fmaf(v.z, v.z, acc);
        acc = fmaf(v.w, v.w, acc);
    }

    float s = block_reduce(acc);
    if (threadIdx.x == 0) partials[blockIdx.x] = s;
}

__global__ __launch_bounds__(BLOCK) void final_kernel(
    const float* __restrict__ partials, float* __restrict__ out)
{
    float acc = 0.f;
    for (int i = threadIdx.x; i < GRID1; i += BLOCK) acc += partials[i];
    float s = block_reduce(acc);
    if (threadIdx.x == 0) out[0] = 0.12f * s;
}

extern "C" void kernel_launch(void* const* d_in, const int* in_sizes, int n_in,
                              void* d_out, int out_size, void* d_ws, size_t ws_size,
                              hipStream_t stream) {
    const float* w = (const float*)d_in[0];   // fc_weights, NUM_FINE*FEAT_DIM fp32
    const float* b = (const float*)d_in[1];   // fc_bias, NUM_FINE fp32
    // d_in[2] (coarse_map) is mathematically irrelevant — see header comment.

    const int nw4 = in_sizes[0] >> 2;   // 12.8e6, fits int
    const int nb4 = in_sizes[1] >> 2;   // 25000

    float* partials = (float*)d_ws;     // GRID1 floats; fully overwritten by
                                        // stage 1 before stage 2 reads them
    float* out = (float*)d_out;

    sq_partial_kernel<<<GRID1, BLOCK, 0, stream>>>(
        (const float4*)w, nw4, (const float4*)b, nb4, partials);
    final_kernel<<<1, BLOCK, 0, stream>>>(partials, out);
}